// Round 6
// baseline (59.104 us; speedup 1.0000x reference)
//
#include <hip/hip_runtime.h>
#include <math.h>

typedef float f32x8 __attribute__((ext_vector_type(8)));

#define THREADS 256
#define R_OUTER 8
#define TILE    (THREADS * R_OUTER)   // 2048 outer points per block

// Issue 3 scalar loads (wave-uniform inner-point data) and wait once.
// SMEM pipe, not LDS, not VMEM. Early-clobber: outputs must not alias inputs.
__device__ __forceinline__ void s_load_group(
    const float* pa, const float* pb, const float* pc,
    f32x8& a, f32x8& b, f32x8& c)
{
    asm volatile(
        "s_load_dwordx8 %0, %3, 0x0\n\t"
        "s_load_dwordx8 %1, %4, 0x0\n\t"
        "s_load_dwordx8 %2, %5, 0x0\n\t"
        "s_waitcnt lgkmcnt(0)"
        : "=&s"(a), "=&s"(b), "=&s"(c)
        : "s"(pa), "s"(pb), "s"(pc));
}

__device__ __forceinline__ float min3f(float a, float b, float c) {
    float d;
    asm("v_min3_f32 %0, %1, %2, %3" : "=v"(d) : "v"(a), "v"(b), "v"(c));
    return d;
}

// Precompute inner-point coefficients a=-2x, b=-2y, c=x^2+y^2 into padded
// segments: q-seg [0, L0), p-seg [L0, L0+L1). Pad entries get c=+huge.
__global__ __launch_bounds__(256) void chamfer_prep(
    const float2* __restrict__ p, int n_p,
    const float2* __restrict__ q, int n_q,
    int L0, int Ltot,
    float* __restrict__ A, float* __restrict__ B, float* __restrict__ C)
{
    const int i = blockIdx.x * 256 + threadIdx.x;
    if (i >= Ltot) return;
    float x = 0.f, y = 0.f; int valid = 0;
    if (i < L0) {
        if (i < n_q) { float2 v = q[i]; x = v.x; y = v.y; valid = 1; }
    } else {
        const int j = i - L0;
        if (j < n_p) { float2 v = p[j]; x = v.x; y = v.y; valid = 1; }
    }
    A[i] = -2.f * x;
    B[i] = -2.f * y;
    C[i] = valid ? fmaf(x, x, y * y) : 3.0e37f;
}

// min_j |p - q_j|^2 = |p|^2 + min_j (c_j + a_j*px + b_j*py)
// Inner data via SGPR (s_load): VALU is the only hot pipe. No LDS, no barriers.
__global__ __launch_bounds__(THREADS) void chamfer_main(
    const float2* __restrict__ p, int n_p,
    const float2* __restrict__ q, int n_q,
    const float* __restrict__ Aarr, const float* __restrict__ Barr,
    const float* __restrict__ Carr,
    int chunk0, int chunk1, int nsplit,
    float* __restrict__ wsMin)   // [nsplit][n_p + n_q]
{
    const int side  = blockIdx.z;           // 0: outer=p inner=q, 1: outer=q inner=p
    const int tile  = blockIdx.x;
    const int split = blockIdx.y;
    const float2* __restrict__ outer = side ? q : p;
    const int n_outer = side ? n_q : n_p;
    if (tile * TILE >= n_outer) return;     // uniform whole-block OOB
    const int chunk   = side ? chunk1 : chunk0;
    const int segbase = side ? nsplit * chunk0 : 0;
    const int jlo     = segbase + split * chunk;
    const int tid     = threadIdx.x;

    float px[R_OUTER], py[R_OUTER], m[R_OUTER];
    #pragma unroll
    for (int r = 0; r < R_OUTER; ++r) {
        const int idx = tile * TILE + r * THREADS + tid;
        float2 pp = (idx < n_outer) ? outer[idx] : make_float2(0.f, 0.f);
        px[r] = pp.x; py[r] = pp.y; m[r] = 3.0e38f;
    }

    const float* pa = Aarr + jlo;
    const float* pb = Barr + jlo;
    const float* pc = Carr + jlo;

    for (int g = 0; g < chunk; g += 8) {
        f32x8 A8, B8, C8;
        s_load_group(pa + g, pb + g, pc + g, A8, B8, C8);
        #pragma unroll
        for (int jj = 0; jj < 8; jj += 2) {
            const float a0 = A8[jj], a1 = A8[jj + 1];
            const float b0 = B8[jj], b1 = B8[jj + 1];
            float vc0 = C8[jj];     asm("" : "+v"(vc0));  // pin c into VGPR:
            float vc1 = C8[jj + 1]; asm("" : "+v"(vc1));  // fma = 1 SGPR + 2 VGPR
            #pragma unroll
            for (int r = 0; r < R_OUTER; ++r) {
                float t0 = fmaf(b0, py[r], vc0);
                t0       = fmaf(a0, px[r], t0);
                float t1 = fmaf(b1, py[r], vc1);
                t1       = fmaf(a1, px[r], t1);
                m[r] = min3f(m[r], t0, t1);
            }
        }
    }

    const int total = n_p + n_q;
    float* __restrict__ wrow =
        wsMin + (size_t)split * total + (side ? n_p : 0);
    #pragma unroll
    for (int r = 0; r < R_OUTER; ++r) {
        const int idx = tile * TILE + r * THREADS + tid;
        if (idx < n_outer) {
            const float hp = fmaf(px[r], px[r], py[r] * py[r]);
            wrow[idx] = m[r] + hp;   // pure store, deterministic
        }
    }
}

// fold nsplit rows per point, sqrt, block partial sums
__global__ __launch_bounds__(256) void chamfer_reduce(
    const float* __restrict__ wsMin, int total, int nsplit,
    float* __restrict__ block_sums)
{
    const int i = blockIdx.x * 256 + threadIdx.x;
    float d = 0.f;
    if (i < total) {
        float mv = 3.0e38f;
        #pragma unroll 16
        for (int j = 0; j < nsplit; ++j)
            mv = fminf(mv, wsMin[(size_t)j * total + i]);
        d = sqrtf(fmaxf(mv, 0.f));
    }
    #pragma unroll
    for (int off = 32; off > 0; off >>= 1) d += __shfl_down(d, off);
    __shared__ float s[4];
    if ((threadIdx.x & 63) == 0) s[threadIdx.x >> 6] = d;
    __syncthreads();
    if (threadIdx.x == 0) block_sums[blockIdx.x] = (s[0] + s[1]) + (s[2] + s[3]);
}

__global__ __launch_bounds__(256) void chamfer_final(
    const float* __restrict__ block_sums, int n, float* __restrict__ out)
{
    float d = 0.f;
    for (int k = threadIdx.x; k < n; k += 256) d += block_sums[k];
    #pragma unroll
    for (int off = 32; off > 0; off >>= 1) d += __shfl_down(d, off);
    __shared__ float s[4];
    if ((threadIdx.x & 63) == 0) s[threadIdx.x >> 6] = d;
    __syncthreads();
    if (threadIdx.x == 0) out[0] = (s[0] + s[1]) + (s[2] + s[3]);
}

extern "C" void kernel_launch(void* const* d_in, const int* in_sizes, int n_in,
                              void* d_out, int out_size, void* d_ws, size_t ws_size,
                              hipStream_t stream) {
    const float2* p = (const float2*)d_in[0];   // (16384, 2) f32
    const float2* q = (const float2*)d_in[1];   // (16384, 2) f32
    const int N = in_sizes[0] / 2;
    const int M = in_sizes[1] / 2;
    float* out = (float*)d_out;

    const int total = N + M;
    const int nb    = (total + 255) / 256;

    // pick nsplit to fit ws: 3 coeff segments + nsplit*total ws matrix + bsum
    int nsplit = 128, chunk0, chunk1;
    size_t L0, L1;
    for (;;) {
        chunk0 = ((M + nsplit - 1) / nsplit + 7) & ~7;   // inner = q (side 0)
        chunk1 = ((N + nsplit - 1) / nsplit + 7) & ~7;   // inner = p (side 1)
        L0 = (size_t)nsplit * chunk0;
        L1 = (size_t)nsplit * chunk1;
        size_t need = (3 * (L0 + L1) + (size_t)nsplit * total + nb) * sizeof(float);
        if (need <= ws_size || nsplit == 1) break;
        nsplit >>= 1;
    }
    const size_t L = L0 + L1;

    float* A     = (float*)d_ws;
    float* B     = A + L;
    float* C     = B + L;
    float* wsMin = C + L;
    float* bsum  = wsMin + (size_t)nsplit * total;

    const int prep_blocks = (int)((L + 255) / 256);
    hipLaunchKernelGGL(chamfer_prep, dim3(prep_blocks), dim3(256), 0, stream,
                       p, N, q, M, (int)L0, (int)L, A, B, C);

    const int tA = (N + TILE - 1) / TILE;
    const int tB = (M + TILE - 1) / TILE;
    dim3 g1(tA > tB ? tA : tB, nsplit, 2);
    hipLaunchKernelGGL(chamfer_main, g1, dim3(THREADS), 0, stream,
                       p, N, q, M, A, B, C, chunk0, chunk1, nsplit, wsMin);

    hipLaunchKernelGGL(chamfer_reduce, dim3(nb), dim3(256), 0, stream,
                       wsMin, total, nsplit, bsum);
    hipLaunchKernelGGL(chamfer_final, dim3(1), dim3(256), 0, stream, bsum, nb, out);
}

// Round 7
// 46.605 us; speedup vs baseline: 1.2682x; 1.2682x over previous
//
#include <hip/hip_runtime.h>
#include <math.h>

typedef float f32x2 __attribute__((ext_vector_type(2)));

#define THREADS   256
#define R_OUTER   16
#define TILE      (THREADS * R_OUTER)   // 4096 outer points per block
#define MAX_STAGE 1024                  // inner points staged per pass (12 KB LDS)
#define NSPLIT    128

__device__ __forceinline__ f32x2 pk_fma(f32x2 a, f32x2 b, f32x2 c) {
    f32x2 d;
    asm("v_pk_fma_f32 %0, %1, %2, %3" : "=v"(d) : "v"(a), "v"(b), "v"(c));
    return d;
}
__device__ __forceinline__ float min3f(float a, float b, float c) {
    float d;
    asm("v_min3_f32 %0, %1, %2, %3" : "=v"(d) : "v"(a), "v"(b), "v"(c));
    return d;
}

// init per-point min slots to +huge (float bits, atomicMin(int) folds them)
__global__ __launch_bounds__(256) void chamfer_init(int* __restrict__ w, int n) {
    const int i = blockIdx.x * 256 + threadIdx.x;
    if (i < n) w[i] = __float_as_int(3.0e38f);
}

// min_j |p - q_j|^2 = |p|^2 + min_j (c_j + a_j*px + b_j*py),
// a = -2 qx, b = -2 qy, c = qx^2 + qy^2 (staged in LDS SoA, broadcast reads).
// Split results folded with atomicMin on int-viewed non-negative floats
// (bit order == value order; min commutative/idempotent -> deterministic).
__global__ __launch_bounds__(THREADS) void chamfer_main(
    const float2* __restrict__ p, int n_p,
    const float2* __restrict__ q, int n_q,
    int nsplit, int* __restrict__ ws_min)   // [n_p + n_q] float-as-int
{
    const int side = blockIdx.z;
    const float2* __restrict__ outer = side ? q : p;
    const float2* __restrict__ inner = side ? p : q;
    const int n_outer = side ? n_q : n_p;
    const int n_inner = side ? n_p : n_q;
    int* __restrict__ wbase = ws_min + (side ? n_p : 0);

    const int tile = blockIdx.x;
    if (tile * TILE >= n_outer) return;          // uniform whole-block OOB
    const int split = blockIdx.y;
    const int tid   = threadIdx.x;

    // this split's inner range (chunk multiple of 4; splits may overlap-pad)
    const int chunk = ((n_inner + nsplit - 1) / nsplit + 3) & ~3;
    const int jlo   = split * chunk;

    // R_OUTER outer points per thread (broadcast pairs for pk_fma)
    f32x2 px2[R_OUTER], py2[R_OUTER];
    float m0[R_OUTER], m1[R_OUTER];
    #pragma unroll
    for (int r = 0; r < R_OUTER; ++r) {
        const int idx = tile * TILE + r * THREADS + tid;
        float2 pp = (idx < n_outer) ? outer[idx] : make_float2(0.f, 0.f);
        px2[r] = (f32x2){pp.x, pp.x};
        py2[r] = (f32x2){pp.y, pp.y};
        m0[r]  = 3.0e38f;
        m1[r]  = 3.0e38f;
    }

    __shared__ __align__(16) float sA[MAX_STAGE];
    __shared__ __align__(16) float sB[MAX_STAGE];
    __shared__ __align__(16) float sC[MAX_STAGE];

    for (int base = jlo; base < jlo + chunk; base += MAX_STAGE) {
        const int len = min(MAX_STAGE, jlo + chunk - base);   // multiple of 4

        // stage: 2 points per thread-iteration, float2 LDS writes
        for (int k = tid; k < (len >> 1); k += THREADS) {
            const int pt = base + (k << 1);
            float x0, y0, x1, y1; int v0, v1;
            if (pt + 1 < n_inner) {
                float4 v = *(const float4*)&inner[pt];
                x0 = v.x; y0 = v.y; x1 = v.z; y1 = v.w; v0 = v1 = 1;
            } else if (pt < n_inner) {
                float2 a = inner[pt];
                x0 = a.x; y0 = a.y; x1 = 0.f; y1 = 0.f; v0 = 1; v1 = 0;
            } else {
                x0 = y0 = x1 = y1 = 0.f; v0 = v1 = 0;
            }
            *(float2*)&sA[k << 1] = make_float2(-2.f * x0, -2.f * x1);
            *(float2*)&sB[k << 1] = make_float2(-2.f * y0, -2.f * y1);
            *(float2*)&sC[k << 1] = make_float2(
                v0 ? fmaf(x0, x0, y0 * y0) : 3.0e37f,
                v1 ? fmaf(x1, x1, y1 * y1) : 3.0e37f);
        }
        __syncthreads();

        const int n4 = len >> 2;
        #pragma unroll 2
        for (int k4 = 0; k4 < n4; ++k4) {
            float4 A = ((const float4*)sA)[k4];   // uniform addr -> broadcast
            float4 B = ((const float4*)sB)[k4];
            float4 C = ((const float4*)sC)[k4];
            f32x2 alo = (f32x2){A.x, A.y}, ahi = (f32x2){A.z, A.w};
            f32x2 blo = (f32x2){B.x, B.y}, bhi = (f32x2){B.z, B.w};
            f32x2 clo = (f32x2){C.x, C.y}, chi = (f32x2){C.z, C.w};
            #pragma unroll
            for (int r = 0; r < R_OUTER; ++r) {
                f32x2 t0 = pk_fma(blo, py2[r], clo);
                t0 = pk_fma(alo, px2[r], t0);
                f32x2 t1 = pk_fma(bhi, py2[r], chi);
                t1 = pk_fma(ahi, px2[r], t1);
                m0[r] = min3f(m0[r], t0.x, t0.y);
                m1[r] = min3f(m1[r], t1.x, t1.y);
            }
        }
        __syncthreads();
    }

    // epilogue: add |p|^2, fold across splits (fire-and-forget atomics)
    #pragma unroll
    for (int r = 0; r < R_OUTER; ++r) {
        const int idx = tile * TILE + r * THREADS + tid;
        if (idx < n_outer) {
            const float px = px2[r].x, py = py2[r].x;
            const float hp = fmaf(px, px, py * py);
            const float v  = fminf(m0[r], m1[r]) + hp;
            atomicMin(&wbase[idx], __float_as_int(v));
        }
    }
}

// per-point sqrt + block partial sums
__global__ __launch_bounds__(256) void chamfer_reduce(
    const int* __restrict__ ws_min, int total_pts,
    float* __restrict__ block_sums)
{
    const int i = blockIdx.x * 256 + threadIdx.x;
    float d = 0.f;
    if (i < total_pts) {
        float mv = __int_as_float(ws_min[i]);
        d = sqrtf(fmaxf(mv, 0.f));
    }
    #pragma unroll
    for (int off = 32; off > 0; off >>= 1) d += __shfl_down(d, off);
    __shared__ float s[4];
    if ((threadIdx.x & 63) == 0) s[threadIdx.x >> 6] = d;
    __syncthreads();
    if (threadIdx.x == 0) block_sums[blockIdx.x] = (s[0] + s[1]) + (s[2] + s[3]);
}

__global__ __launch_bounds__(256) void chamfer_final(
    const float* __restrict__ block_sums, int n, float* __restrict__ out)
{
    float d = 0.f;
    for (int k = threadIdx.x; k < n; k += 256) d += block_sums[k];
    #pragma unroll
    for (int off = 32; off > 0; off >>= 1) d += __shfl_down(d, off);
    __shared__ float s[4];
    if ((threadIdx.x & 63) == 0) s[threadIdx.x >> 6] = d;
    __syncthreads();
    if (threadIdx.x == 0) out[0] = (s[0] + s[1]) + (s[2] + s[3]);
}

extern "C" void kernel_launch(void* const* d_in, const int* in_sizes, int n_in,
                              void* d_out, int out_size, void* d_ws, size_t ws_size,
                              hipStream_t stream) {
    const float2* p = (const float2*)d_in[0];   // (16384, 2) f32
    const float2* q = (const float2*)d_in[1];   // (16384, 2) f32
    const int N = in_sizes[0] / 2;
    const int M = in_sizes[1] / 2;
    float* out = (float*)d_out;

    const int total = N + M;
    const int nb    = (total + 255) / 256;

    int*   wmin = (int*)d_ws;                   // total ints (float bits)
    float* bsum = (float*)d_ws + total;         // nb floats

    hipLaunchKernelGGL(chamfer_init, dim3(nb), dim3(256), 0, stream, wmin, total);

    const int nsplit = NSPLIT;
    const int tA = (N + TILE - 1) / TILE;
    const int tB = (M + TILE - 1) / TILE;
    dim3 g1(tA > tB ? tA : tB, nsplit, 2);
    hipLaunchKernelGGL(chamfer_main, g1, dim3(THREADS), 0, stream,
                       p, N, q, M, nsplit, wmin);

    hipLaunchKernelGGL(chamfer_reduce, dim3(nb), dim3(256), 0, stream,
                       wmin, total, bsum);
    hipLaunchKernelGGL(chamfer_final, dim3(1), dim3(256), 0, stream, bsum, nb, out);
}